// Round 20
// baseline (88.339 us; speedup 1.0000x reference)
//
#include <hip/hip_runtime.h>

#define N_BONDS 50000
#define N_EDGES 600000
#define R_BONDS 8
#define BONDS_PER_BLOCK 32     // 4 waves * 8 bonds
#define STARTS_BLOCKS ((N_EDGES + 255) / 256)          // 2344
#define PREMUL_BLOCKS ((N_BONDS + 31) / 32)            // 1563
#define MAIN_BLOCKS ((N_BONDS + BONDS_PER_BLOCK - 1) / BONDS_PER_BLOCK)  // 1563

typedef float f4 __attribute__((ext_vector_type(4)));
typedef unsigned short u16x4 __attribute__((ext_vector_type(4)));

__device__ __forceinline__ float bcastf(float v, int l) {
    return __builtin_bit_cast(float, __builtin_amdgcn_readlane(__builtin_bit_cast(int, v), l));
}
__device__ __forceinline__ f4 f4zero() { return (f4){0.f, 0.f, 0.f, 0.f}; }
__device__ __forceinline__ void fma4(f4& a, float s, const f4& b) {
    a.x = fmaf(s, b.x, a.x); a.y = fmaf(s, b.y, a.y);
    a.z = fmaf(s, b.z, a.z); a.w = fmaf(s, b.w, a.w);
}
__device__ __forceinline__ float bf2f(unsigned short u) {
    return __builtin_bit_cast(float, ((unsigned)u) << 16);
}
__device__ __forceinline__ unsigned short f2bf(float f) {   // RNE
    unsigned u = __builtin_bit_cast(unsigned, f);
    return (unsigned short)((u + 0x7fffu + ((u >> 16) & 1u)) >> 16);
}
__device__ __forceinline__ f4 cvt4(u16x4 u) {
    return (f4){bf2f(u.x), bf2f(u.y), bf2f(u.z), bf2f(u.w)};
}

// ---- K0: starts[] + bondKb = bf16(bond @ Ktop)  (R13-proven) ----
__global__ __launch_bounds__(256)
void prep(const int* __restrict__ edges, int* __restrict__ starts,
          const float* __restrict__ bond, const float* __restrict__ Kmat,
          unsigned short* __restrict__ bondKb) {
    __shared__ float ldsK[64 * 64];
    const int tid = threadIdx.x;

    if (blockIdx.x < STARTS_BLOCKS) {
        const int e = blockIdx.x * 256 + tid;
        if (e >= N_EDGES) return;
        const int2* edges2 = (const int2*)edges;
        const int s  = edges2[e].x;
        const int sp = (e == 0) ? -1 : edges2[e - 1].x;
        for (int b = sp + 1; b <= s; ++b) starts[b] = e;
        if (e == N_EDGES - 1)
            for (int b = s + 1; b <= N_BONDS; ++b) starts[b] = N_EDGES;
        return;
    }

    const int bid  = blockIdx.x - STARTS_BLOCKS;
    const int lane = tid & 63;
    const int wid  = tid >> 6;
    {
        const f4* K4 = (const f4*)Kmat;            // Ktop = first 1024 f4
        f4* L4 = (f4*)ldsK;
        #pragma unroll
        for (int i = 0; i < 4; ++i) L4[tid + i * 256] = K4[tid + i * 256];
    }
    __syncthreads();
    const int row0 = bid * 32 + wid * 8;
    if (row0 >= N_BONDS) return;

    float rowv[8], acc[8];
    #pragma unroll
    for (int r = 0; r < 8; ++r) {
        int ri = row0 + r; if (ri >= N_BONDS) ri = N_BONDS - 1;
        rowv[r] = bond[ri * 64 + lane];
        acc[r]  = 0.f;
    }
    #pragma unroll 4
    for (int d = 0; d < 64; ++d) {
        const float k = ldsK[d * 64 + lane];       // lane = output unit
        #pragma unroll
        for (int r = 0; r < 8; ++r)
            acc[r] = fmaf(bcastf(rowv[r], d), k, acc[r]);
    }
    #pragma unroll
    for (int r = 0; r < 8; ++r)
        if (row0 + r < N_BONDS)
            bondKb[(row0 + r) * 64 + lane] = f2bf(acc[r]);
}

// ---- K1: PURE gather segsum. Only bondKb gathers (+ tiny idx loads) on chip. ----
__global__ __launch_bounds__(256, 8)   // no LDS, no barrier, VGPR<=64
void gather_segsum(const unsigned short* __restrict__ bondKb, // [N_BONDS][64] bf16
                   const int* __restrict__ edges,
                   const int* __restrict__ starts,
                   float* __restrict__ Gsum)                  // [N_BONDS][64]
{
    const int tid  = threadIdx.x;
    const int lane = tid & 63;
    const int wid  = tid >> 6;
    const int fl   = lane & 15;
    const int sg   = lane >> 4;

    const int b0 = blockIdx.x * BONDS_PER_BLOCK + wid * R_BONDS;
    if (b0 >= N_BONDS) return;

    int st[R_BONDS + 1];                               // SGPR, static-indexed only
    #pragma unroll
    for (int r = 0; r <= R_BONDS; ++r) {
        int ix = b0 + r; if (ix > N_BONDS) ix = N_BONDS;
        st[r] = __builtin_amdgcn_readfirstlane(starts[ix]);
    }
    const int eb    = st[0];
    const int total = st[R_BONDS] - eb;
    const int nq    = (total + 3) >> 2;

    const u16x4* bk4 = (const u16x4*)bondKb;

    float slot[R_BONDS];
    f4 aX = f4zero();
    int r = 0, cs = 0, bnd = st[1] - eb;

    auto txr = [&](f4 v) -> float {
        v.x += __shfl_xor(v.x, 16); v.y += __shfl_xor(v.y, 16);
        v.z += __shfl_xor(v.z, 16); v.w += __shfl_xor(v.w, 16);
        v.x += __shfl_xor(v.x, 32); v.y += __shfl_xor(v.y, 32);
        v.z += __shfl_xor(v.z, 32); v.w += __shfl_xor(v.w, 32);
        const int src = lane >> 2;
        const float s0 = __shfl(v.x, src), s1 = __shfl(v.y, src);
        const float s2 = __shfl(v.z, src), s3 = __shfl(v.w, src);
        const float r01 = (lane & 1) ? s1 : s0;
        const float r23 = (lane & 1) ? s3 : s2;
        return (lane & 2) ? r23 : r01;
    };
    auto slowpath = [&](int q, f4 XV) {
        const int qe = q + sg;
        while (true) {
            const float m = (qe >= cs && qe < bnd) ? 1.f : 0.f;
            fma4(aX, m, XV);
            if (bnd > q + 4) break;
            const float tX = txr(aX);
            #pragma unroll
            for (int rr = 0; rr < R_BONDS; ++rr) if (rr == r) slot[rr] = tX;
            aX = f4zero();
            cs = bnd;
            ++r;
            if (r >= R_BONDS) { bnd = 0x7fffffff; break; }
            #pragma unroll
            for (int rr = 2; rr <= R_BONDS; ++rr) if (r + 1 == rr) bnd = st[rr] - eb;
        }
    };
    auto accX = [&](int Q, f4 XV) {
        const int q_ = Q * 4;
        if (q_ + 4 <= bnd) aX += XV;
        else slowpath(q_, XV);
    };
    auto loadIdx = [&](int Q) -> int {
        if (Q >= nq) return 0;                         // uniform guard
        int e = 4 * Q + sg;
        e = (e < total) ? e : total - 1;
        return edges[2 * (eb + e) + 1];                // subgroup-uniform dword
    };

    if (nq > 0) {
        int ia0 = loadIdx(0), ia1 = loadIdx(1), ia2 = loadIdx(2), ia3 = loadIdx(3);
        int ib0 = loadIdx(4), ib1 = loadIdx(5), ib2 = loadIdx(6), ib3 = loadIdx(7);
        for (int Q = 0; Q < nq; Q += 4) {
            u16x4 x0 = bk4[ia0 * 16 + fl];
            u16x4 x1 = (Q + 1 < nq) ? bk4[ia1 * 16 + fl] : (u16x4){0,0,0,0};
            u16x4 x2 = (Q + 2 < nq) ? bk4[ia2 * 16 + fl] : (u16x4){0,0,0,0};
            u16x4 x3 = (Q + 3 < nq) ? bk4[ia3 * 16 + fl] : (u16x4){0,0,0,0};
            ia0 = ib0; ia1 = ib1; ia2 = ib2; ia3 = ib3;
            ib0 = loadIdx(Q + 8);  ib1 = loadIdx(Q + 9);
            ib2 = loadIdx(Q + 10); ib3 = loadIdx(Q + 11);
            accX(Q + 0, cvt4(x0));
            if (Q + 1 < nq) accX(Q + 1, cvt4(x1));
            if (Q + 2 < nq) accX(Q + 2, cvt4(x2));
            if (Q + 3 < nq) accX(Q + 3, cvt4(x3));
        }
    }

    {
        const float tX = txr(aX);
        #pragma unroll
        for (int rr = 0; rr < R_BONDS; ++rr) {
            if (rr == r)     slot[rr] = tX;
            else if (rr > r) slot[rr] = 0.f;
        }
    }
    #pragma unroll
    for (int rr = 0; rr < R_BONDS; ++rr)
        if (b0 + rr < N_BONDS)
            __builtin_nontemporal_store(slot[rr], &Gsum[(b0 + rr) * 64 + lane]);
}

// ---- K2: PURE linear stream: sph segsum + Kbot matvec + Gsum + bias -> out ----
__global__ __launch_bounds__(256, 6)
void stream_segsum_mm(const float* __restrict__ sph,
                      const float* __restrict__ Kmat,
                      const float* __restrict__ bias,
                      const int* __restrict__ starts,
                      const float* __restrict__ Gsum,
                      float* __restrict__ out)
{
    __shared__ float ldsK[64 * 64];   // 16 KB: Kbot
    const int tid  = threadIdx.x;
    const int lane = tid & 63;
    const int wid  = tid >> 6;
    const int fl   = lane & 15;
    const int sg   = lane >> 4;

    {   // stage Kbot (rows 64..127 = f4 index 1024..2047)
        const f4* K4 = (const f4*)Kmat;
        f4* L4 = (f4*)ldsK;
        #pragma unroll
        for (int i = 0; i < 4; ++i) L4[tid + i * 256] = K4[1024 + tid + i * 256];
    }
    __syncthreads();                                   // only barrier

    const int b0 = blockIdx.x * BONDS_PER_BLOCK + wid * R_BONDS;
    if (b0 >= N_BONDS) return;

    int st[R_BONDS + 1];
    #pragma unroll
    for (int r = 0; r <= R_BONDS; ++r) {
        int ix = b0 + r; if (ix > N_BONDS) ix = N_BONDS;
        st[r] = __builtin_amdgcn_readfirstlane(starts[ix]);
    }
    const int eb    = st[0];
    const int total = st[R_BONDS] - eb;
    const int nq    = (total + 3) >> 2;

    const f4* sph4 = (const f4*)sph;

    float slotS[R_BONDS];
    f4 aX = f4zero();
    int r = 0, cs = 0, bnd = st[1] - eb;

    auto txr = [&](f4 v) -> float {
        v.x += __shfl_xor(v.x, 16); v.y += __shfl_xor(v.y, 16);
        v.z += __shfl_xor(v.z, 16); v.w += __shfl_xor(v.w, 16);
        v.x += __shfl_xor(v.x, 32); v.y += __shfl_xor(v.y, 32);
        v.z += __shfl_xor(v.z, 32); v.w += __shfl_xor(v.w, 32);
        const int src = lane >> 2;
        const float s0 = __shfl(v.x, src), s1 = __shfl(v.y, src);
        const float s2 = __shfl(v.z, src), s3 = __shfl(v.w, src);
        const float r01 = (lane & 1) ? s1 : s0;
        const float r23 = (lane & 1) ? s3 : s2;
        return (lane & 2) ? r23 : r01;
    };
    auto slowpath = [&](int q, f4 XV) {
        const int qe = q + sg;
        while (true) {
            const float m = (qe >= cs && qe < bnd) ? 1.f : 0.f;
            fma4(aX, m, XV);
            if (bnd > q + 4) break;
            const float tX = txr(aX);
            #pragma unroll
            for (int rr = 0; rr < R_BONDS; ++rr) if (rr == r) slotS[rr] = tX;
            aX = f4zero();
            cs = bnd;
            ++r;
            if (r >= R_BONDS) { bnd = 0x7fffffff; break; }
            #pragma unroll
            for (int rr = 2; rr <= R_BONDS; ++rr) if (r + 1 == rr) bnd = st[rr] - eb;
        }
    };
    auto accX = [&](int Q, f4 XV) {
        const int q_ = Q * 4;
        if (q_ + 4 <= bnd) aX += XV;
        else slowpath(q_, XV);
    };

    // index-free pure linear stream, 4-deep
    for (int Q = 0; Q < nq; Q += 4) {
        int e0 = 4 * Q + sg;       e0 = (e0 < total) ? e0 : total - 1;
        int e1 = 4 * (Q + 1) + sg; e1 = (e1 < total) ? e1 : total - 1;
        int e2 = 4 * (Q + 2) + sg; e2 = (e2 < total) ? e2 : total - 1;
        int e3 = 4 * (Q + 3) + sg; e3 = (e3 < total) ? e3 : total - 1;
        f4 x0 = sph4[(eb + e0) * 16 + fl];
        f4 x1 = (Q + 1 < nq) ? sph4[(eb + e1) * 16 + fl] : f4zero();
        f4 x2 = (Q + 2 < nq) ? sph4[(eb + e2) * 16 + fl] : f4zero();
        f4 x3 = (Q + 3 < nq) ? sph4[(eb + e3) * 16 + fl] : f4zero();
        accX(Q + 0, x0);
        if (Q + 1 < nq) accX(Q + 1, x1);
        if (Q + 2 < nq) accX(Q + 2, x2);
        if (Q + 3 < nq) accX(Q + 3, x3);
    }

    {
        const float tX = txr(aX);
        #pragma unroll
        for (int rr = 0; rr < R_BONDS; ++rr) {
            if (rr == r)     slotS[rr] = tX;
            else if (rr > r) slotS[rr] = 0.f;
        }
    }

    // Gsum rows: linear loads issued BEFORE the matvec (hidden under it)
    float gv[R_BONDS];
    #pragma unroll
    for (int rr = 0; rr < R_BONDS; ++rr) {
        int ri = b0 + rr; if (ri >= N_BONDS) ri = N_BONDS - 1;
        gv[rr] = Gsum[ri * 64 + lane];
    }

    float acc[R_BONDS];
    const float bl = bias[lane];
    #pragma unroll
    for (int rr = 0; rr < R_BONDS; ++rr) acc[rr] = bl;

    #pragma unroll 4
    for (int d = 0; d < 64; ++d) {
        const float kb = ldsK[d * 64 + lane];          // 2-way bank alias: free
        #pragma unroll
        for (int rr = 0; rr < R_BONDS; ++rr)
            acc[rr] = fmaf(bcastf(slotS[rr], d), kb, acc[rr]);
    }

    #pragma unroll
    for (int rr = 0; rr < R_BONDS; ++rr)
        if (b0 + rr < N_BONDS)
            __builtin_nontemporal_store(acc[rr] + gv[rr], &out[(b0 + rr) * 64 + lane]);
}

extern "C" void kernel_launch(void* const* d_in, const int* in_sizes, int n_in,
                              void* d_out, int out_size, void* d_ws, size_t ws_size,
                              hipStream_t stream) {
    const float* bond  = (const float*)d_in[0];
    const float* sph   = (const float*)d_in[1];
    const int*   edges = (const int*)d_in[2];
    const float* Kmat  = (const float*)d_in[3];
    const float* bias  = (const float*)d_in[4];
    float* out = (float*)d_out;

    const size_t rowBytes = (size_t)N_BONDS * 64 * sizeof(float);   // 12.8 MB
    int*            starts = (int*)d_ws;                            // 200 KB
    float*          Gsum   = (float*)((char*)d_ws + 262144);
    unsigned short* bondKb = (unsigned short*)((char*)d_ws + 262144 + rowBytes);

    prep<<<STARTS_BLOCKS + PREMUL_BLOCKS, 256, 0, stream>>>(edges, starts,
                                                            bond, Kmat, bondKb);
    gather_segsum<<<MAIN_BLOCKS, 256, 0, stream>>>(bondKb, edges, starts, Gsum);
    stream_segsum_mm<<<MAIN_BLOCKS, 256, 0, stream>>>(sph, Kmat, bias, starts,
                                                      Gsum, out);
}